// Round 16
// baseline (156.141 us; speedup 1.0000x reference)
//
#include <hip/hip_runtime.h>
#include <stdint.h>

typedef __attribute__((ext_vector_type(8))) short bf16x8;
typedef __attribute__((ext_vector_type(4))) float f32x4;

__device__ __forceinline__ unsigned short f2bf(float f) {
  unsigned int u = __builtin_bit_cast(unsigned int, f);
  u += 0x7fffu + ((u >> 16) & 1u);
  return (unsigned short)(u >> 16);
}

__device__ __forceinline__ float bf2f(unsigned short u) {
  unsigned int x = ((unsigned int)u) << 16;
  return __builtin_bit_cast(float, x);
}

__device__ __forceinline__ void gload16(const void* g, void* l) {
  __builtin_amdgcn_global_load_lds(
      (const __attribute__((address_space(1))) void*)g,
      (__attribute__((address_space(3))) void*)l, 16, 0, 0);
}

// XCD-aware bijective remap (T1): dispatch position i -> tile j so that
// tile-sharing blocks land on the SAME XCD's L2. Requires nwg % 8 == 0.
__device__ __forceinline__ int xcd_remap(int i, int nwg) {
  return (i & 7) * (nwg >> 3) + (i >> 3);
}

// ---------------- merged f32 -> bf16 conversion (one dispatch) -------------
__global__ void cvt_all(const float* __restrict__ enc,
                        const float* __restrict__ cost,
                        const float* __restrict__ wq,
                        const float* __restrict__ wk,
                        const float* __restrict__ wv,
                        const float* __restrict__ fcw,
                        const float* __restrict__ w1,
                        const float* __restrict__ w2,
                        unsigned short* __restrict__ enc_bf,
                        unsigned short* __restrict__ cost_bf,
                        unsigned short* __restrict__ wqkv_bf,
                        unsigned short* __restrict__ fcw_bf,
                        unsigned short* __restrict__ w1_bf,
                        unsigned short* __restrict__ w2_bf) {
  const int i = blockIdx.x * 256 + threadIdx.x;
  constexpr int E0 = 1048576;       // enc  (8192*512/4)
  constexpr int E1 = E0 + 2097152;  // cost (8*1024*1024/4)
  constexpr int E2 = E1 + 65536;    // wq
  constexpr int E3 = E2 + 65536;    // wk
  constexpr int E4 = E3 + 65536;    // wv
  constexpr int E5 = E4 + 65536;    // fcw
  constexpr int E6 = E5 + 262144;   // w1
  constexpr int E7 = E6 + 262144;   // w2
  const float* in;
  unsigned short* out;
  int base;
  float scale = 1.0f;
  if (i < E0)      { in = enc;  out = enc_bf;            base = 0;  }
  else if (i < E1) { in = cost; out = cost_bf;           base = E0; scale = 1.44269504f; }
  else if (i < E2) { in = wq;   out = wqkv_bf;           base = E1; }
  else if (i < E3) { in = wk;   out = wqkv_bf + 262144;  base = E2; }
  else if (i < E4) { in = wv;   out = wqkv_bf + 524288;  base = E3; }
  else if (i < E5) { in = fcw;  out = fcw_bf;            base = E4; }
  else if (i < E6) { in = w1;   out = w1_bf;             base = E5; }
  else if (i < E7) { in = w2;   out = w2_bf;             base = E6; }
  else return;
  const int k = i - base;
  float4 v = ((const float4*)in)[k];
  ushort4 o;
  o.x = f2bf(v.x * scale);
  o.y = f2bf(v.y * scale);
  o.z = f2bf(v.z * scale);
  o.w = f2bf(v.w * scale);
  ((ushort4*)out)[k] = o;
}

// ---------------- GEMM 128x128: C = A * B^T  (round-10 form + T1) ----------
// EPI: 2 = +bias,relu -> bf16, 5 = fused QKV {Qb,Kb,Vt}
template <int EPI>
__global__ __launch_bounds__(256, 2) void gemm_bt(
    const unsigned short* __restrict__ A, const unsigned short* __restrict__ B,
    void* __restrict__ C, const float* __restrict__ bias, int M, int N, int K) {
  __shared__ unsigned short Al[2][128 * 32];
  __shared__ unsigned short Bl[2][128 * 32];
  const int tid = threadIdx.x;
  const int lane = tid & 63;
  const int wid = tid >> 6;
  const int wr = wid >> 1;
  const int wc = wid & 1;
  // T1 remap: tile-sharing blocks (same y-panel) -> same XCD
  const int nwg = gridDim.x * gridDim.y;
  const int j_ = xcd_remap(blockIdx.y * gridDim.x + blockIdx.x, nwg);
  const int m0 = (j_ / gridDim.x) * 128;
  const int n0 = (j_ % gridDim.x) * 128;

  f32x4 acc[4][4];
#pragma unroll
  for (int i = 0; i < 4; ++i)
#pragma unroll
    for (int j = 0; j < 4; ++j) acc[i][j] = f32x4{0.f, 0.f, 0.f, 0.f};

  const int srow = wid * 32 + (lane >> 2);
  const int scol = (lane & 3) * 8;
  const unsigned short* Ag = A + (size_t)(m0 + srow) * K + scol;
  const unsigned short* Bg = B + (size_t)(n0 + srow) * K + scol;
  const size_t K16 = (size_t)16 * K;

  auto stage = [&](int buf, int kt) {
    unsigned short* Ald = &Al[buf][wid * 1024];
    unsigned short* Bld = &Bl[buf][wid * 1024];
    gload16(Ag + kt, Ald);
    gload16(Ag + K16 + kt, Ald + 512);
    gload16(Bg + kt, Bld);
    gload16(Bg + K16 + kt, Bld + 512);
  };

  const int ko = (lane >> 4) * 8;
  const int arow = wr * 64 + (lane & 15);
  const int brow = wc * 64 + (lane & 15);

  stage(0, 0);
  __syncthreads();
  for (int kt = 0, it = 0; kt < K; kt += 32, ++it) {
    const int cur = it & 1;
    if (kt + 32 < K) stage(cur ^ 1, kt + 32);
    bf16x8 af[4], bf[4];
#pragma unroll
    for (int mi = 0; mi < 4; ++mi)
      af[mi] = *(const bf16x8*)&Al[cur][(arow + mi * 16) * 32 + ko];
#pragma unroll
    for (int ni = 0; ni < 4; ++ni)
      bf[ni] = *(const bf16x8*)&Bl[cur][(brow + ni * 16) * 32 + ko];
#pragma unroll
    for (int mi = 0; mi < 4; ++mi)
#pragma unroll
      for (int ni = 0; ni < 4; ++ni)
        acc[mi][ni] = __builtin_amdgcn_mfma_f32_16x16x32_bf16(
            af[mi], bf[ni], acc[mi][ni], 0, 0, 0);
    __syncthreads();
  }

  const int rl = (lane >> 4) * 4;
  const int cl = lane & 15;
#pragma unroll
  for (int mi = 0; mi < 4; ++mi) {
#pragma unroll
    for (int ni = 0; ni < 4; ++ni) {
      const int r0 = m0 + wr * 64 + mi * 16 + rl;
      const int c = n0 + wc * 64 + ni * 16 + cl;
      if (EPI == 5 && c >= 1024) {
        unsigned short* Vt = (unsigned short*)C + (size_t)2 * 8192 * 512;
        const int cc = c - 1024;
        ushort4 pk;
        pk.x = f2bf(acc[mi][ni][0]);
        pk.y = f2bf(acc[mi][ni][1]);
        pk.z = f2bf(acc[mi][ni][2]);
        pk.w = f2bf(acc[mi][ni][3]);
        const int b_ = r0 >> 10, s_ = r0 & 1023, h_ = cc >> 6, dd = cc & 63;
        *(ushort4*)(Vt + ((size_t)((b_ * 8 + h_) * 64 + dd) * 1024 + s_)) = pk;
      } else if (EPI == 5) {
        unsigned short* dst =
            (c < 512) ? (unsigned short*)C + (size_t)r0 * 512 + c
                      : (unsigned short*)C + (size_t)8192 * 512 +
                            (size_t)r0 * 512 + (c - 512);
#pragma unroll
        for (int j = 0; j < 4; ++j) dst[(size_t)j * 512] = f2bf(acc[mi][ni][j]);
      } else {
#pragma unroll
        for (int j = 0; j < 4; ++j) {
          float v = acc[mi][ni][j];
          if (EPI == 2) v = fmaxf(v + bias[c], 0.f);
          ((unsigned short*)C)[(size_t)(r0 + j) * N + c] = f2bf(v);
        }
      }
    }
  }
}

// ---------------- GEMM 64x128 (N=512 ops), BK=64 + T1 ----------------------
// BK 32->64: halves the barrier/drain count per unit work (the measured
// bottleneck after T1 — m233: stage+drain+barrier dominates 2-phase loops).
// LDS 48 KB total, grid is the occupancy cap (2 blocks/CU) so no loss.
// EPI: 0 = bf16 out, 6 = +bias -> bf16
template <int EPI>
__global__ __launch_bounds__(256, 2) void gemm_bt64(
    const unsigned short* __restrict__ A, const unsigned short* __restrict__ B,
    void* __restrict__ C, const float* __restrict__ bias, int M, int N, int K) {
  __shared__ unsigned short Al[2][64 * 64];   // 8 KB per buf
  __shared__ unsigned short Bl[2][128 * 64];  // 16 KB per buf
  const int tid = threadIdx.x;
  const int lane = tid & 63;
  const int wid = tid >> 6;
  const int nwg = gridDim.x * gridDim.y;
  const int j_ = xcd_remap(blockIdx.y * gridDim.x + blockIdx.x, nwg);
  const int m0 = (j_ / gridDim.x) * 64;
  const int n0 = (j_ % gridDim.x) * 128;

  f32x4 acc[4][2];
#pragma unroll
  for (int i = 0; i < 4; ++i)
#pragma unroll
    for (int j = 0; j < 2; ++j) acc[i][j] = f32x4{0.f, 0.f, 0.f, 0.f};

  // staging: rows t>>3 (+32 per extra load), cols (t&7)*8; dest linear
  // (lane-delta = lane*16 B per gload_lds requirement).
  const int srow = tid >> 3;       // 0..31
  const int scol = (tid & 7) * 8;  // 0..56
  const unsigned short* Ag = A + (size_t)(m0 + srow) * K + scol;
  const unsigned short* Bg = B + (size_t)(n0 + srow) * K + scol;

  auto stage = [&](int buf, int kt) {
#pragma unroll
    for (int i = 0; i < 2; ++i)
      gload16(Ag + (size_t)(32 * i) * K + kt, &Al[buf][wid * 512 + i * 2048]);
#pragma unroll
    for (int i = 0; i < 4; ++i)
      gload16(Bg + (size_t)(32 * i) * K + kt, &Bl[buf][wid * 512 + i * 2048]);
  };

  const int ko = (lane >> 4) * 8;
  const int cl16 = lane & 15;

  stage(0, 0);
  __syncthreads();
  for (int kt = 0, it = 0; kt < K; kt += 64, ++it) {
    const int cur = it & 1;
    if (kt + 64 < K) stage(cur ^ 1, kt + 64);
#pragma unroll
    for (int kh = 0; kh < 2; ++kh) {
      bf16x8 af[4], bf[2];
#pragma unroll
      for (int mi = 0; mi < 4; ++mi)
        af[mi] =
            *(const bf16x8*)&Al[cur][(mi * 16 + cl16) * 64 + kh * 32 + ko];
#pragma unroll
      for (int ni = 0; ni < 2; ++ni)
        bf[ni] = *(const bf16x8*)&Bl[cur][(wid * 32 + ni * 16 + cl16) * 64 +
                                          kh * 32 + ko];
#pragma unroll
      for (int mi = 0; mi < 4; ++mi)
#pragma unroll
        for (int ni = 0; ni < 2; ++ni)
          acc[mi][ni] = __builtin_amdgcn_mfma_f32_16x16x32_bf16(
              af[mi], bf[ni], acc[mi][ni], 0, 0, 0);
    }
    __syncthreads();
  }

  const int rl = (lane >> 4) * 4;
#pragma unroll
  for (int mi = 0; mi < 4; ++mi) {
#pragma unroll
    for (int ni = 0; ni < 2; ++ni) {
      const int r0 = m0 + mi * 16 + rl;
      const int c = n0 + wid * 32 + ni * 16 + cl16;
#pragma unroll
      for (int j = 0; j < 4; ++j) {
        float v = acc[mi][ni][j];
        if (EPI == 6) v += bias[c];
        ((unsigned short*)C)[(size_t)(r0 + j) * N + c] = f2bf(v);
      }
    }
  }
}

// ---------------- flash attention with additive cost bias (r14, unchanged) -
__global__ __launch_bounds__(512, 4) void attn_kernel(
    const unsigned short* __restrict__ Q, const unsigned short* __restrict__ K,
    const unsigned short* __restrict__ V,   // Vt layout [B*H*64, 1024]
    const unsigned short* __restrict__ Cb,  // cost*log2e bf16 [B,1024,1024]
    unsigned short* __restrict__ ctx) {
  __shared__ unsigned short Kl[2][4096];  // 64x64, col^=(row&7)*8
  __shared__ unsigned short Vl[2][4096];  // same swizzle
  __shared__ unsigned short Cl[8192];     // 128q x 64k, col^=(row&7)*8
  __shared__ unsigned short P[8][1024];   // per-wave [16 q][64 k], col^=(q&7)*8
  const int tid = threadIdx.x, lane = tid & 63, wid = tid >> 6;
  // T1 remap: the 8 q-blocks of one (b,h) -> same XCD (K/V L2-resident)
  const int j_ = xcd_remap(blockIdx.y * 8 + blockIdx.x, 512);
  const int bh = j_ >> 3, b = bh >> 3, h = bh & 7;
  const int q0 = (j_ & 7) * 128;
  const int qw = q0 + wid * 16;
  const int cl = lane & 15, gl = lane >> 4;

  const unsigned short* qp =
      Q + (size_t)(b * 1024 + qw + cl) * 512 + h * 64 + gl * 8;
  const bf16x8 qf0 = *(const bf16x8*)qp;
  const bf16x8 qf1 = *(const bf16x8*)(qp + 32);

  f32x4 acc[4];
  float lsum = 0.f;
#pragma unroll
  for (int i = 0; i < 4; ++i) acc[i] = f32x4{0.f, 0.f, 0.f, 0.f};

  const int srow = tid >> 3;  // 0..63
  const int swzc = ((tid & 7) * 8) ^ ((srow & 7) << 3);
  const unsigned short* Ksrc =
      K + (size_t)(b * 1024 + srow) * 512 + h * 64 + swzc;
  const unsigned short* Vsrc = V + (size_t)(bh * 64 + srow) * 1024 + swzc;
  const unsigned short* Csrc =
      Cb + (size_t)(b * 1024 + q0 + srow) * 1024 + swzc;

  auto stage_kv = [&](int buf, int k0) {
    gload16(Ksrc + (size_t)k0 * 512, &Kl[buf][wid * 512]);
    gload16(Vsrc + k0, &Vl[buf][wid * 512]);
  };
  auto stage_c = [&](int k0) {
    gload16(Csrc + k0, &Cl[wid * 512]);
    gload16(Csrc + (size_t)64 * 1024 + k0, &Cl[4096 + wid * 512]);
  };

  const int ks = (cl & 7) << 3;        // K/V read XOR (row&7 = cl&7)
  const int pswz = (cl & 7) << 3;      // P/cost row XOR (q&7 = cl&7)
  const int crow = wid * 16 + cl;      // this lane's q row in Cl

  stage_kv(0, 0);
  stage_c(0);
  __syncthreads();

  for (int t = 0; t < 16; ++t) {
    const int cur = t & 1;
    if (t < 15) stage_kv(cur ^ 1, (t + 1) * 64);

    // ---- swapped QK^T + exp2: lane holds scores for q = cl ----
#pragma unroll
    for (int ni = 0; ni < 4; ++ni) {
      const int krow = ni * 16 + cl;
      bf16x8 k0f = *(const bf16x8*)&Kl[cur][krow * 64 + ((gl * 8) ^ ks)];
      bf16x8 k1f = *(const bf16x8*)&Kl[cur][krow * 64 + ((32 + gl * 8) ^ ks)];
      f32x4 t2 = f32x4{0.f, 0.f, 0.f, 0.f};
      t2 = __builtin_amdgcn_mfma_f32_16x16x32_bf16(k0f, qf0, t2, 0, 0, 0);
      t2 = __builtin_amdgcn_mfma_f32_16x16x32_bf16(k1f, qf1, t2, 0, 0, 0);
      const uint2 cpk = *(const uint2*)&Cl[crow * 64 + ((ni * 16 + gl * 4) ^ pswz)];
      float p0, p1, p2, p3;
      {
        float e0 = __builtin_fmaf(t2[0], 0.18033688f, bf2f((unsigned short)(cpk.x & 0xffff)));
        float e1 = __builtin_fmaf(t2[1], 0.18033688f, bf2f((unsigned short)(cpk.x >> 16)));
        float e2 = __builtin_fmaf(t2[2], 0.18033688f, bf2f((unsigned short)(cpk.y & 0xffff)));
        float e3 = __builtin_fmaf(t2[3], 0.18033688f, bf2f((unsigned short)(cpk.y >> 16)));
        asm("v_exp_f32 %0, %1" : "=v"(p0) : "v"(e0));
        asm("v_exp_f32 %0, %1" : "=v"(p1) : "v"(e1));
        asm("v_exp_f32 %0, %1" : "=v"(p2) : "v"(e2));
        asm("v_exp_f32 %0, %1" : "=v"(p3) : "v"(e3));
      }
      lsum += (p0 + p1) + (p2 + p3);
      uint32_t lo, hi;
      asm("v_cvt_pk_bf16_f32 %0, %1, %2" : "=v"(lo) : "v"(p0), "v"(p1));
      asm("v_cvt_pk_bf16_f32 %0, %1, %2" : "=v"(hi) : "v"(p2), "v"(p3));
      *(uint2*)&P[wid][cl * 64 + ((ni * 16 + gl * 4) ^ pswz)] = uint2{lo, hi};
    }
    __builtin_amdgcn_sched_barrier(0);
    __builtin_amdgcn_s_barrier();
    __builtin_amdgcn_sched_barrier(0);
    if (t < 15) stage_c((t + 1) * 64);  // re-stage cost under PV

    bf16x8 pf0 = *(const bf16x8*)&P[wid][cl * 64 + ((gl * 8) ^ pswz)];
    bf16x8 pf1 = *(const bf16x8*)&P[wid][cl * 64 + ((32 + gl * 8) ^ pswz)];
#pragma unroll
    for (int nv = 0; nv < 4; ++nv) {
      const int vrow = nv * 16 + cl;
      bf16x8 v0f = *(const bf16x8*)&Vl[cur][vrow * 64 + ((gl * 8) ^ ks)];
      bf16x8 v1f = *(const bf16x8*)&Vl[cur][vrow * 64 + ((32 + gl * 8) ^ ks)];
      acc[nv] =
          __builtin_amdgcn_mfma_f32_16x16x32_bf16(pf0, v0f, acc[nv], 0, 0, 0);
      acc[nv] =
          __builtin_amdgcn_mfma_f32_16x16x32_bf16(pf1, v1f, acc[nv], 0, 0, 0);
    }
    __syncthreads();
  }

  lsum += __shfl_xor(lsum, 16);
  lsum += __shfl_xor(lsum, 32);
  const float linv = 1.0f / lsum;
  float linvw[4];
#pragma unroll
  for (int j = 0; j < 4; ++j) linvw[j] = __shfl(linv, gl * 4 + j);
#pragma unroll
  for (int nv = 0; nv < 4; ++nv)
#pragma unroll
    for (int j = 0; j < 4; ++j) {
      float v = acc[nv][j] * linvw[j];
      ctx[(size_t)(b * 1024 + qw + gl * 4 + j) * 512 + h * 64 + nv * 16 + cl] =
          f2bf(v);
    }
}

// ---------------- fused residual + LayerNorm (rows of 512, bf16 in) --------
template <int OUT_F32>
__global__ __launch_bounds__(256) void ln_kernel(
    const unsigned short* __restrict__ x1, const unsigned short* __restrict__ x2,
    const float* __restrict__ g, const float* __restrict__ bt,
    void* __restrict__ out) {
  const int lane = threadIdx.x & 63, wid = threadIdx.x >> 6;
  const int row = blockIdx.x * 4 + wid;
  const bf16x8 a = *(const bf16x8*)(x1 + (size_t)row * 512 + lane * 8);
  const bf16x8 bb = *(const bf16x8*)(x2 + (size_t)row * 512 + lane * 8);
  float x[8];
#pragma unroll
  for (int i = 0; i < 8; ++i)
    x[i] = bf2f((unsigned short)a[i]) + bf2f((unsigned short)bb[i]);
  float sum = 0.f, sq = 0.f;
#pragma unroll
  for (int i = 0; i < 8; ++i) {
    sum += x[i];
    sq += x[i] * x[i];
  }
#pragma unroll
  for (int m = 1; m <= 32; m <<= 1) {
    sum += __shfl_xor(sum, m);
    sq += __shfl_xor(sq, m);
  }
  const float mean = sum * (1.f / 512.f);
  const float var = sq * (1.f / 512.f) - mean * mean;
  const float rstd = rsqrtf(var + 1e-6f);
  float y[8];
#pragma unroll
  for (int i = 0; i < 8; ++i) {
    const int c = lane * 8 + i;
    y[i] = (x[i] - mean) * rstd * g[c] + bt[c];
  }
  if (OUT_F32) {
    float4* op = (float4*)((float*)out + (size_t)row * 512);
    op[lane * 2] = make_float4(y[0], y[1], y[2], y[3]);
    op[lane * 2 + 1] = make_float4(y[4], y[5], y[6], y[7]);
  } else {
    bf16x8 o;
#pragma unroll
    for (int i = 0; i < 8; ++i) o[i] = (short)f2bf(y[i]);
    *(bf16x8*)((unsigned short*)out + (size_t)row * 512 + lane * 8) = o;
  }
}

extern "C" void kernel_launch(void* const* d_in, const int* in_sizes, int n_in,
                              void* d_out, int out_size, void* d_ws,
                              size_t ws_size, hipStream_t stream) {
  const float* enc = (const float*)d_in[0];
  const float* cost = (const float*)d_in[1];
  const float* wq = (const float*)d_in[2];
  const float* wk = (const float*)d_in[3];
  const float* wv = (const float*)d_in[4];
  const float* fcw = (const float*)d_in[5];
  const float* ln1g = (const float*)d_in[6];
  const float* ln1b = (const float*)d_in[7];
  const float* w1 = (const float*)d_in[8];
  const float* b1 = (const float*)d_in[9];
  const float* w2 = (const float*)d_in[10];
  const float* b2 = (const float*)d_in[11];
  const float* ln2g = (const float*)d_in[12];
  const float* ln2b = (const float*)d_in[13];

  char* ws = (char*)d_ws;
  size_t off = 0;
  auto alloc = [&](size_t n) {
    void* p = ws + off;
    off += (n + 255) & ~(size_t)255;
    return p;
  };
  const size_t MD = 8192ull * 512;    // M x D elements
  const size_t MF = 8192ull * 2048;   // M x DF elements
  unsigned short* enc_bf = (unsigned short*)alloc(MD * 2);
  unsigned short* wqkv_bf = (unsigned short*)alloc(3 * 512 * 512 * 2);
  unsigned short* fcw_bf = (unsigned short*)alloc(512 * 512 * 2);
  unsigned short* w1_bf = (unsigned short*)alloc(2048 * 512 * 2);
  unsigned short* w2_bf = (unsigned short*)alloc(512 * 2048 * 2);
  // Qb, Kb, Vt MUST be contiguous (EPI=5 computes Kb/Vt from Qb base).
  unsigned short* Qb = (unsigned short*)alloc(MD * 2 * 3);
  unsigned short* Kb = Qb + MD;
  unsigned short* Vt = Kb + MD;
  unsigned short* ctx_bf = (unsigned short*)alloc(MD * 2);
  unsigned short* fc_bf = (unsigned short*)alloc(MD * 2);
  unsigned short* attn_bf = (unsigned short*)alloc(MD * 2);
  unsigned short* ffn_bf = (unsigned short*)alloc(MD * 2);
  unsigned short* h_bf = (unsigned short*)alloc(MF * 2);
  // cost_bf aliases h_bf: cost_bf used only before FFN1 produces h_bf.
  unsigned short* cost_bf = h_bf;

  // one merged conversion dispatch (cost pre-scaled by log2e)
  cvt_all<<<15360, 256, 0, stream>>>(enc, cost, wq, wk, wv, fcw, w1, w2,
                                     enc_bf, cost_bf, wqkv_bf, fcw_bf, w1_bf,
                                     w2_bf);

  // fused Q/K/V projection (N = 1536)
  gemm_bt<5><<<dim3(12, 64), 256, 0, stream>>>(enc_bf, wqkv_bf, Qb, nullptr,
                                               8192, 1536, 512);
  // attention (128 q-rows per block, 8 waves)
  attn_kernel<<<dim3(8, 64), 512, 0, stream>>>(Qb, Kb, Vt, cost_bf, ctx_bf);
  // fc projection (bf16 out), LN1 (+enc residual) -> bf16
  gemm_bt64<0><<<dim3(4, 128), 256, 0, stream>>>(ctx_bf, fcw_bf, fc_bf,
                                                 nullptr, 8192, 512, 512);
  ln_kernel<0><<<2048, 256, 0, stream>>>(fc_bf, enc_bf, ln1g, ln1b, attn_bf);
  // FFN
  gemm_bt<2><<<dim3(16, 64), 256, 0, stream>>>(attn_bf, w1_bf, h_bf, b1, 8192,
                                               2048, 512);
  gemm_bt64<6><<<dim3(4, 128), 256, 0, stream>>>(h_bf, w2_bf, ffn_bf, b2, 8192,
                                                 512, 2048);
  // LN2 (+attn_out residual) -> final f32 output
  ln_kernel<1><<<2048, 256, 0, stream>>>(ffn_bf, attn_bf, ln2g, ln2b, d_out);
}

// Round 17
// 142.429 us; speedup vs baseline: 1.0963x; 1.0963x over previous
//
#include <hip/hip_runtime.h>
#include <stdint.h>

typedef __attribute__((ext_vector_type(8))) short bf16x8;
typedef __attribute__((ext_vector_type(4))) float f32x4;

__device__ __forceinline__ unsigned short f2bf(float f) {
  unsigned int u = __builtin_bit_cast(unsigned int, f);
  u += 0x7fffu + ((u >> 16) & 1u);
  return (unsigned short)(u >> 16);
}

__device__ __forceinline__ float bf2f(unsigned short u) {
  unsigned int x = ((unsigned int)u) << 16;
  return __builtin_bit_cast(float, x);
}

__device__ __forceinline__ void gload16(const void* g, void* l) {
  __builtin_amdgcn_global_load_lds(
      (const __attribute__((address_space(1))) void*)g,
      (__attribute__((address_space(3))) void*)l, 16, 0, 0);
}

// XCD-aware bijective remap (T1): dispatch position i -> tile j so that
// tile-sharing blocks land on the SAME XCD's L2. Requires nwg % 8 == 0.
__device__ __forceinline__ int xcd_remap(int i, int nwg) {
  return (i & 7) * (nwg >> 3) + (i >> 3);
}

// ---------------- merged f32 -> bf16 conversion (one dispatch) -------------
__global__ void cvt_all(const float* __restrict__ enc,
                        const float* __restrict__ cost,
                        const float* __restrict__ wq,
                        const float* __restrict__ wk,
                        const float* __restrict__ wv,
                        const float* __restrict__ fcw,
                        const float* __restrict__ w1,
                        const float* __restrict__ w2,
                        unsigned short* __restrict__ enc_bf,
                        unsigned short* __restrict__ cost_bf,
                        unsigned short* __restrict__ wqkv_bf,
                        unsigned short* __restrict__ fcw_bf,
                        unsigned short* __restrict__ w1_bf,
                        unsigned short* __restrict__ w2_bf) {
  const int i = blockIdx.x * 256 + threadIdx.x;
  constexpr int E0 = 1048576;       // enc  (8192*512/4)
  constexpr int E1 = E0 + 2097152;  // cost (8*1024*1024/4)
  constexpr int E2 = E1 + 65536;    // wq
  constexpr int E3 = E2 + 65536;    // wk
  constexpr int E4 = E3 + 65536;    // wv
  constexpr int E5 = E4 + 65536;    // fcw
  constexpr int E6 = E5 + 262144;   // w1
  constexpr int E7 = E6 + 262144;   // w2
  const float* in;
  unsigned short* out;
  int base;
  float scale = 1.0f;
  if (i < E0)      { in = enc;  out = enc_bf;            base = 0;  }
  else if (i < E1) { in = cost; out = cost_bf;           base = E0; scale = 1.44269504f; }
  else if (i < E2) { in = wq;   out = wqkv_bf;           base = E1; }
  else if (i < E3) { in = wk;   out = wqkv_bf + 262144;  base = E2; }
  else if (i < E4) { in = wv;   out = wqkv_bf + 524288;  base = E3; }
  else if (i < E5) { in = fcw;  out = fcw_bf;            base = E4; }
  else if (i < E6) { in = w1;   out = w1_bf;             base = E5; }
  else if (i < E7) { in = w2;   out = w2_bf;             base = E6; }
  else return;
  const int k = i - base;
  float4 v = ((const float4*)in)[k];
  ushort4 o;
  o.x = f2bf(v.x * scale);
  o.y = f2bf(v.y * scale);
  o.z = f2bf(v.z * scale);
  o.w = f2bf(v.w * scale);
  ((ushort4*)out)[k] = o;
}

// ---------------- GEMM 128x128: C = A * B^T  (round-10 form + T1) ----------
// EPI: 2 = +bias,relu -> bf16, 5 = fused QKV {Qb,Kb,Vt}
template <int EPI>
__global__ __launch_bounds__(256, 2) void gemm_bt(
    const unsigned short* __restrict__ A, const unsigned short* __restrict__ B,
    void* __restrict__ C, const float* __restrict__ bias, int M, int N, int K) {
  __shared__ unsigned short Al[2][128 * 32];
  __shared__ unsigned short Bl[2][128 * 32];
  const int tid = threadIdx.x;
  const int lane = tid & 63;
  const int wid = tid >> 6;
  const int wr = wid >> 1;
  const int wc = wid & 1;
  // T1 remap: tile-sharing blocks (same y-panel) -> same XCD
  const int nwg = gridDim.x * gridDim.y;
  const int j_ = xcd_remap(blockIdx.y * gridDim.x + blockIdx.x, nwg);
  const int m0 = (j_ / gridDim.x) * 128;
  const int n0 = (j_ % gridDim.x) * 128;

  f32x4 acc[4][4];
#pragma unroll
  for (int i = 0; i < 4; ++i)
#pragma unroll
    for (int j = 0; j < 4; ++j) acc[i][j] = f32x4{0.f, 0.f, 0.f, 0.f};

  const int srow = wid * 32 + (lane >> 2);
  const int scol = (lane & 3) * 8;
  const unsigned short* Ag = A + (size_t)(m0 + srow) * K + scol;
  const unsigned short* Bg = B + (size_t)(n0 + srow) * K + scol;
  const size_t K16 = (size_t)16 * K;

  auto stage = [&](int buf, int kt) {
    unsigned short* Ald = &Al[buf][wid * 1024];
    unsigned short* Bld = &Bl[buf][wid * 1024];
    gload16(Ag + kt, Ald);
    gload16(Ag + K16 + kt, Ald + 512);
    gload16(Bg + kt, Bld);
    gload16(Bg + K16 + kt, Bld + 512);
  };

  const int ko = (lane >> 4) * 8;
  const int arow = wr * 64 + (lane & 15);
  const int brow = wc * 64 + (lane & 15);

  stage(0, 0);
  __syncthreads();
  for (int kt = 0, it = 0; kt < K; kt += 32, ++it) {
    const int cur = it & 1;
    if (kt + 32 < K) stage(cur ^ 1, kt + 32);
    bf16x8 af[4], bf[4];
#pragma unroll
    for (int mi = 0; mi < 4; ++mi)
      af[mi] = *(const bf16x8*)&Al[cur][(arow + mi * 16) * 32 + ko];
#pragma unroll
    for (int ni = 0; ni < 4; ++ni)
      bf[ni] = *(const bf16x8*)&Bl[cur][(brow + ni * 16) * 32 + ko];
#pragma unroll
    for (int mi = 0; mi < 4; ++mi)
#pragma unroll
      for (int ni = 0; ni < 4; ++ni)
        acc[mi][ni] = __builtin_amdgcn_mfma_f32_16x16x32_bf16(
            af[mi], bf[ni], acc[mi][ni], 0, 0, 0);
    __syncthreads();
  }

  const int rl = (lane >> 4) * 4;
  const int cl = lane & 15;
#pragma unroll
  for (int mi = 0; mi < 4; ++mi) {
#pragma unroll
    for (int ni = 0; ni < 4; ++ni) {
      const int r0 = m0 + wr * 64 + mi * 16 + rl;
      const int c = n0 + wc * 64 + ni * 16 + cl;
      if (EPI == 5 && c >= 1024) {
        unsigned short* Vt = (unsigned short*)C + (size_t)2 * 8192 * 512;
        const int cc = c - 1024;
        ushort4 pk;
        pk.x = f2bf(acc[mi][ni][0]);
        pk.y = f2bf(acc[mi][ni][1]);
        pk.z = f2bf(acc[mi][ni][2]);
        pk.w = f2bf(acc[mi][ni][3]);
        const int b_ = r0 >> 10, s_ = r0 & 1023, h_ = cc >> 6, dd = cc & 63;
        *(ushort4*)(Vt + ((size_t)((b_ * 8 + h_) * 64 + dd) * 1024 + s_)) = pk;
      } else if (EPI == 5) {
        unsigned short* dst =
            (c < 512) ? (unsigned short*)C + (size_t)r0 * 512 + c
                      : (unsigned short*)C + (size_t)8192 * 512 +
                            (size_t)r0 * 512 + (c - 512);
#pragma unroll
        for (int j = 0; j < 4; ++j) dst[(size_t)j * 512] = f2bf(acc[mi][ni][j]);
      } else {
#pragma unroll
        for (int j = 0; j < 4; ++j) {
          float v = acc[mi][ni][j];
          if (EPI == 2) v = fmaxf(v + bias[c], 0.f);
          ((unsigned short*)C)[(size_t)(r0 + j) * N + c] = f2bf(v);
        }
      }
    }
  }
}

// ---------------- GEMM 64x128 (N=512 ops), BK=64 + T1 + T2 swizzle ---------
// BK=64 halves barriers/FETCH (r16: FETCH 67.6->24.6 MB) but its 128B rows
// made fragment reads a 16-way bank conflict (9.4M cycles). Fix: store
// LDS[row][col ^ (row&7)*8] via pre-swizzled GLOBAL source (linear LDS dest,
// rule #21) and read with the same XOR ((row&7) = (cl16&7), lane-constant).
// Post-swizzle: 8 lanes per 16B slot x 8 slots = uniform 8 acc/bank = optimal.
// EPI: 0 = bf16 out, 6 = +bias -> bf16
template <int EPI>
__global__ __launch_bounds__(256, 2) void gemm_bt64(
    const unsigned short* __restrict__ A, const unsigned short* __restrict__ B,
    void* __restrict__ C, const float* __restrict__ bias, int M, int N, int K) {
  __shared__ unsigned short Al[2][64 * 64];   // 8 KB per buf
  __shared__ unsigned short Bl[2][128 * 64];  // 16 KB per buf
  const int tid = threadIdx.x;
  const int lane = tid & 63;
  const int wid = tid >> 6;
  const int nwg = gridDim.x * gridDim.y;
  const int j_ = xcd_remap(blockIdx.y * gridDim.x + blockIdx.x, nwg);
  const int m0 = (j_ / gridDim.x) * 64;
  const int n0 = (j_ % gridDim.x) * 128;

  f32x4 acc[4][2];
#pragma unroll
  for (int i = 0; i < 4; ++i)
#pragma unroll
    for (int j = 0; j < 2; ++j) acc[i][j] = f32x4{0.f, 0.f, 0.f, 0.f};

  // staging: pre-swizzled global col; LDS dest linear (lane*16B).
  const int srow = tid >> 3;                               // 0..31
  const int scol = ((tid & 7) * 8) ^ ((srow & 7) * 8);     // swizzled
  const unsigned short* Ag = A + (size_t)(m0 + srow) * K + scol;
  const unsigned short* Bg = B + (size_t)(n0 + srow) * K + scol;

  auto stage = [&](int buf, int kt) {
#pragma unroll
    for (int i = 0; i < 2; ++i)
      gload16(Ag + (size_t)(32 * i) * K + kt, &Al[buf][wid * 512 + i * 2048]);
#pragma unroll
    for (int i = 0; i < 4; ++i)
      gload16(Bg + (size_t)(32 * i) * K + kt, &Bl[buf][wid * 512 + i * 2048]);
  };

  const int ko = (lane >> 4) * 8;
  const int cl16 = lane & 15;
  const int fswz = (cl16 & 7) * 8;  // row&7 = cl16&7 for all fragment rows

  stage(0, 0);
  __syncthreads();
  for (int kt = 0, it = 0; kt < K; kt += 64, ++it) {
    const int cur = it & 1;
    if (kt + 64 < K) stage(cur ^ 1, kt + 64);
#pragma unroll
    for (int kh = 0; kh < 2; ++kh) {
      bf16x8 af[4], bf[2];
#pragma unroll
      for (int mi = 0; mi < 4; ++mi)
        af[mi] = *(const bf16x8*)&Al[cur][(mi * 16 + cl16) * 64 +
                                          ((kh * 32 + ko) ^ fswz)];
#pragma unroll
      for (int ni = 0; ni < 2; ++ni)
        bf[ni] = *(const bf16x8*)&Bl[cur][(wid * 32 + ni * 16 + cl16) * 64 +
                                          ((kh * 32 + ko) ^ fswz)];
#pragma unroll
      for (int mi = 0; mi < 4; ++mi)
#pragma unroll
        for (int ni = 0; ni < 2; ++ni)
          acc[mi][ni] = __builtin_amdgcn_mfma_f32_16x16x32_bf16(
              af[mi], bf[ni], acc[mi][ni], 0, 0, 0);
    }
    __syncthreads();
  }

  const int rl = (lane >> 4) * 4;
#pragma unroll
  for (int mi = 0; mi < 4; ++mi) {
#pragma unroll
    for (int ni = 0; ni < 2; ++ni) {
      const int r0 = m0 + mi * 16 + rl;
      const int c = n0 + wid * 32 + ni * 16 + cl16;
#pragma unroll
      for (int j = 0; j < 4; ++j) {
        float v = acc[mi][ni][j];
        if (EPI == 6) v += bias[c];
        ((unsigned short*)C)[(size_t)(r0 + j) * N + c] = f2bf(v);
      }
    }
  }
}

// ---------------- flash attention with additive cost bias (r14, unchanged) -
__global__ __launch_bounds__(512, 4) void attn_kernel(
    const unsigned short* __restrict__ Q, const unsigned short* __restrict__ K,
    const unsigned short* __restrict__ V,   // Vt layout [B*H*64, 1024]
    const unsigned short* __restrict__ Cb,  // cost*log2e bf16 [B,1024,1024]
    unsigned short* __restrict__ ctx) {
  __shared__ unsigned short Kl[2][4096];  // 64x64, col^=(row&7)*8
  __shared__ unsigned short Vl[2][4096];  // same swizzle
  __shared__ unsigned short Cl[8192];     // 128q x 64k, col^=(row&7)*8
  __shared__ unsigned short P[8][1024];   // per-wave [16 q][64 k], col^=(q&7)*8
  const int tid = threadIdx.x, lane = tid & 63, wid = tid >> 6;
  // T1 remap: the 8 q-blocks of one (b,h) -> same XCD (K/V L2-resident)
  const int j_ = xcd_remap(blockIdx.y * 8 + blockIdx.x, 512);
  const int bh = j_ >> 3, b = bh >> 3, h = bh & 7;
  const int q0 = (j_ & 7) * 128;
  const int qw = q0 + wid * 16;
  const int cl = lane & 15, gl = lane >> 4;

  const unsigned short* qp =
      Q + (size_t)(b * 1024 + qw + cl) * 512 + h * 64 + gl * 8;
  const bf16x8 qf0 = *(const bf16x8*)qp;
  const bf16x8 qf1 = *(const bf16x8*)(qp + 32);

  f32x4 acc[4];
  float lsum = 0.f;
#pragma unroll
  for (int i = 0; i < 4; ++i) acc[i] = f32x4{0.f, 0.f, 0.f, 0.f};

  const int srow = tid >> 3;  // 0..63
  const int swzc = ((tid & 7) * 8) ^ ((srow & 7) << 3);
  const unsigned short* Ksrc =
      K + (size_t)(b * 1024 + srow) * 512 + h * 64 + swzc;
  const unsigned short* Vsrc = V + (size_t)(bh * 64 + srow) * 1024 + swzc;
  const unsigned short* Csrc =
      Cb + (size_t)(b * 1024 + q0 + srow) * 1024 + swzc;

  auto stage_kv = [&](int buf, int k0) {
    gload16(Ksrc + (size_t)k0 * 512, &Kl[buf][wid * 512]);
    gload16(Vsrc + k0, &Vl[buf][wid * 512]);
  };
  auto stage_c = [&](int k0) {
    gload16(Csrc + k0, &Cl[wid * 512]);
    gload16(Csrc + (size_t)64 * 1024 + k0, &Cl[4096 + wid * 512]);
  };

  const int ks = (cl & 7) << 3;        // K/V read XOR (row&7 = cl&7)
  const int pswz = (cl & 7) << 3;      // P/cost row XOR (q&7 = cl&7)
  const int crow = wid * 16 + cl;      // this lane's q row in Cl

  stage_kv(0, 0);
  stage_c(0);
  __syncthreads();

  for (int t = 0; t < 16; ++t) {
    const int cur = t & 1;
    if (t < 15) stage_kv(cur ^ 1, (t + 1) * 64);

    // ---- swapped QK^T + exp2: lane holds scores for q = cl ----
#pragma unroll
    for (int ni = 0; ni < 4; ++ni) {
      const int krow = ni * 16 + cl;
      bf16x8 k0f = *(const bf16x8*)&Kl[cur][krow * 64 + ((gl * 8) ^ ks)];
      bf16x8 k1f = *(const bf16x8*)&Kl[cur][krow * 64 + ((32 + gl * 8) ^ ks)];
      f32x4 t2 = f32x4{0.f, 0.f, 0.f, 0.f};
      t2 = __builtin_amdgcn_mfma_f32_16x16x32_bf16(k0f, qf0, t2, 0, 0, 0);
      t2 = __builtin_amdgcn_mfma_f32_16x16x32_bf16(k1f, qf1, t2, 0, 0, 0);
      const uint2 cpk = *(const uint2*)&Cl[crow * 64 + ((ni * 16 + gl * 4) ^ pswz)];
      float p0, p1, p2, p3;
      {
        float e0 = __builtin_fmaf(t2[0], 0.18033688f, bf2f((unsigned short)(cpk.x & 0xffff)));
        float e1 = __builtin_fmaf(t2[1], 0.18033688f, bf2f((unsigned short)(cpk.x >> 16)));
        float e2 = __builtin_fmaf(t2[2], 0.18033688f, bf2f((unsigned short)(cpk.y & 0xffff)));
        float e3 = __builtin_fmaf(t2[3], 0.18033688f, bf2f((unsigned short)(cpk.y >> 16)));
        asm("v_exp_f32 %0, %1" : "=v"(p0) : "v"(e0));
        asm("v_exp_f32 %0, %1" : "=v"(p1) : "v"(e1));
        asm("v_exp_f32 %0, %1" : "=v"(p2) : "v"(e2));
        asm("v_exp_f32 %0, %1" : "=v"(p3) : "v"(e3));
      }
      lsum += (p0 + p1) + (p2 + p3);
      uint32_t lo, hi;
      asm("v_cvt_pk_bf16_f32 %0, %1, %2" : "=v"(lo) : "v"(p0), "v"(p1));
      asm("v_cvt_pk_bf16_f32 %0, %1, %2" : "=v"(hi) : "v"(p2), "v"(p3));
      *(uint2*)&P[wid][cl * 64 + ((ni * 16 + gl * 4) ^ pswz)] = uint2{lo, hi};
    }
    __builtin_amdgcn_sched_barrier(0);
    __builtin_amdgcn_s_barrier();
    __builtin_amdgcn_sched_barrier(0);
    if (t < 15) stage_c((t + 1) * 64);  // re-stage cost under PV

    bf16x8 pf0 = *(const bf16x8*)&P[wid][cl * 64 + ((gl * 8) ^ pswz)];
    bf16x8 pf1 = *(const bf16x8*)&P[wid][cl * 64 + ((32 + gl * 8) ^ pswz)];
#pragma unroll
    for (int nv = 0; nv < 4; ++nv) {
      const int vrow = nv * 16 + cl;
      bf16x8 v0f = *(const bf16x8*)&Vl[cur][vrow * 64 + ((gl * 8) ^ ks)];
      bf16x8 v1f = *(const bf16x8*)&Vl[cur][vrow * 64 + ((32 + gl * 8) ^ ks)];
      acc[nv] =
          __builtin_amdgcn_mfma_f32_16x16x32_bf16(pf0, v0f, acc[nv], 0, 0, 0);
      acc[nv] =
          __builtin_amdgcn_mfma_f32_16x16x32_bf16(pf1, v1f, acc[nv], 0, 0, 0);
    }
    __syncthreads();
  }

  lsum += __shfl_xor(lsum, 16);
  lsum += __shfl_xor(lsum, 32);
  const float linv = 1.0f / lsum;
  float linvw[4];
#pragma unroll
  for (int j = 0; j < 4; ++j) linvw[j] = __shfl(linv, gl * 4 + j);
#pragma unroll
  for (int nv = 0; nv < 4; ++nv)
#pragma unroll
    for (int j = 0; j < 4; ++j) {
      float v = acc[nv][j] * linvw[j];
      ctx[(size_t)(b * 1024 + qw + gl * 4 + j) * 512 + h * 64 + nv * 16 + cl] =
          f2bf(v);
    }
}

// ---------------- fused residual + LayerNorm (rows of 512, bf16 in) --------
template <int OUT_F32>
__global__ __launch_bounds__(256) void ln_kernel(
    const unsigned short* __restrict__ x1, const unsigned short* __restrict__ x2,
    const float* __restrict__ g, const float* __restrict__ bt,
    void* __restrict__ out) {
  const int lane = threadIdx.x & 63, wid = threadIdx.x >> 6;
  const int row = blockIdx.x * 4 + wid;
  const bf16x8 a = *(const bf16x8*)(x1 + (size_t)row * 512 + lane * 8);
  const bf16x8 bb = *(const bf16x8*)(x2 + (size_t)row * 512 + lane * 8);
  float x[8];
#pragma unroll
  for (int i = 0; i < 8; ++i)
    x[i] = bf2f((unsigned short)a[i]) + bf2f((unsigned short)bb[i]);
  float sum = 0.f, sq = 0.f;
#pragma unroll
  for (int i = 0; i < 8; ++i) {
    sum += x[i];
    sq += x[i] * x[i];
  }
#pragma unroll
  for (int m = 1; m <= 32; m <<= 1) {
    sum += __shfl_xor(sum, m);
    sq += __shfl_xor(sq, m);
  }
  const float mean = sum * (1.f / 512.f);
  const float var = sq * (1.f / 512.f) - mean * mean;
  const float rstd = rsqrtf(var + 1e-6f);
  float y[8];
#pragma unroll
  for (int i = 0; i < 8; ++i) {
    const int c = lane * 8 + i;
    y[i] = (x[i] - mean) * rstd * g[c] + bt[c];
  }
  if (OUT_F32) {
    float4* op = (float4*)((float*)out + (size_t)row * 512);
    op[lane * 2] = make_float4(y[0], y[1], y[2], y[3]);
    op[lane * 2 + 1] = make_float4(y[4], y[5], y[6], y[7]);
  } else {
    bf16x8 o;
#pragma unroll
    for (int i = 0; i < 8; ++i) o[i] = (short)f2bf(y[i]);
    *(bf16x8*)((unsigned short*)out + (size_t)row * 512 + lane * 8) = o;
  }
}

extern "C" void kernel_launch(void* const* d_in, const int* in_sizes, int n_in,
                              void* d_out, int out_size, void* d_ws,
                              size_t ws_size, hipStream_t stream) {
  const float* enc = (const float*)d_in[0];
  const float* cost = (const float*)d_in[1];
  const float* wq = (const float*)d_in[2];
  const float* wk = (const float*)d_in[3];
  const float* wv = (const float*)d_in[4];
  const float* fcw = (const float*)d_in[5];
  const float* ln1g = (const float*)d_in[6];
  const float* ln1b = (const float*)d_in[7];
  const float* w1 = (const float*)d_in[8];
  const float* b1 = (const float*)d_in[9];
  const float* w2 = (const float*)d_in[10];
  const float* b2 = (const float*)d_in[11];
  const float* ln2g = (const float*)d_in[12];
  const float* ln2b = (const float*)d_in[13];

  char* ws = (char*)d_ws;
  size_t off = 0;
  auto alloc = [&](size_t n) {
    void* p = ws + off;
    off += (n + 255) & ~(size_t)255;
    return p;
  };
  const size_t MD = 8192ull * 512;    // M x D elements
  const size_t MF = 8192ull * 2048;   // M x DF elements
  unsigned short* enc_bf = (unsigned short*)alloc(MD * 2);
  unsigned short* wqkv_bf = (unsigned short*)alloc(3 * 512 * 512 * 2);
  unsigned short* fcw_bf = (unsigned short*)alloc(512 * 512 * 2);
  unsigned short* w1_bf = (unsigned short*)alloc(2048 * 512 * 2);
  unsigned short* w2_bf = (unsigned short*)alloc(512 * 2048 * 2);
  // Qb, Kb, Vt MUST be contiguous (EPI=5 computes Kb/Vt from Qb base).
  unsigned short* Qb = (unsigned short*)alloc(MD * 2 * 3);
  unsigned short* Kb = Qb + MD;
  unsigned short* Vt = Kb + MD;
  unsigned short* ctx_bf = (unsigned short*)alloc(MD * 2);
  unsigned short* fc_bf = (unsigned short*)alloc(MD * 2);
  unsigned short* attn_bf = (unsigned short*)alloc(MD * 2);
  unsigned short* ffn_bf = (unsigned short*)alloc(MD * 2);
  unsigned short* h_bf = (unsigned short*)alloc(MF * 2);
  // cost_bf aliases h_bf: cost_bf used only before FFN1 produces h_bf.
  unsigned short* cost_bf = h_bf;

  // one merged conversion dispatch (cost pre-scaled by log2e)
  cvt_all<<<15360, 256, 0, stream>>>(enc, cost, wq, wk, wv, fcw, w1, w2,
                                     enc_bf, cost_bf, wqkv_bf, fcw_bf, w1_bf,
                                     w2_bf);

  // fused Q/K/V projection (N = 1536)
  gemm_bt<5><<<dim3(12, 64), 256, 0, stream>>>(enc_bf, wqkv_bf, Qb, nullptr,
                                               8192, 1536, 512);
  // attention (128 q-rows per block, 8 waves)
  attn_kernel<<<dim3(8, 64), 512, 0, stream>>>(Qb, Kb, Vt, cost_bf, ctx_bf);
  // fc projection (bf16 out), LN1 (+enc residual) -> bf16
  gemm_bt64<0><<<dim3(4, 128), 256, 0, stream>>>(ctx_bf, fcw_bf, fc_bf,
                                                 nullptr, 8192, 512, 512);
  ln_kernel<0><<<2048, 256, 0, stream>>>(fc_bf, enc_bf, ln1g, ln1b, attn_bf);
  // FFN
  gemm_bt<2><<<dim3(16, 64), 256, 0, stream>>>(attn_bf, w1_bf, h_bf, b1, 8192,
                                               2048, 512);
  gemm_bt64<6><<<dim3(4, 128), 256, 0, stream>>>(h_bf, w2_bf, ffn_bf, b2, 8192,
                                                 512, 2048);
  // LN2 (+attn_out residual) -> final f32 output
  ln_kernel<1><<<2048, 256, 0, stream>>>(ffn_bf, attn_bf, ln2g, ln2b, d_out);
}